// Round 1
// baseline (229.813 us; speedup 1.0000x reference)
//
#include <hip/hip_runtime.h>
#include <stdint.h>

#define ALPHA 0.2f
#define LOG2E 1.4426950408889634f

typedef __attribute__((ext_vector_type(8))) short short8;
typedef __attribute__((ext_vector_type(4))) float f32x4;
typedef __attribute__((ext_vector_type(4))) int int4v;
typedef __attribute__((ext_vector_type(2))) unsigned int uint2v;

#if __has_builtin(__builtin_amdgcn_exp2f)
#define EXP2(x) __builtin_amdgcn_exp2f(x)
#else
#define EXP2(x) exp2f(x)
#endif

__device__ __forceinline__ unsigned short f2bf(float x){
  union { float f; uint32_t u; } v; v.f = x;
  uint32_t u = v.u;
  u += 0x7FFFu + ((u >> 16) & 1u);
  return (unsigned short)(u >> 16);
}
__device__ __forceinline__ float bf2f(unsigned short s){
  union { uint32_t u; float f; } v; v.u = ((uint32_t)s) << 16; return v.f;
}

// ---- zero acc + Z (8MB + 32KB) ----
__global__ void k_zero(f32x4* p){
  p[blockIdx.x * 256 + threadIdx.x] = (f32x4){0.f, 0.f, 0.f, 0.f};
}

// ---- hamilton^T as bf16 hi/lo planes: hamT[c][k], c<256, k<1024 ----
__global__ void k_ham(const float* __restrict__ W, unsigned short* __restrict__ hi,
                      unsigned short* __restrict__ lo){
  int id = blockIdx.x * 256 + threadIdx.x;   // id = c*1024 + k
  int c = id >> 10, k = id & 1023;
  int b = k >> 8, r = k & 255;
  int cb = c >> 6, col = c & 63;
  const int   comp[4][4] = {{0,1,2,3},{1,0,3,2},{2,3,0,1},{3,2,1,0}};
  const float sgn [4][4] = {{1.f,-1.f,-1.f,-1.f},{1.f,1.f,-1.f,1.f},
                            {1.f,1.f,1.f,-1.f},{1.f,-1.f,1.f,1.f}};
  float v = sgn[b][cb] * W[r * 256 + comp[b][cb] * 64 + col];
  unsigned short h = f2bf(v);
  hi[id] = h;
  lo[id] = f2bf(v - bf2f(h));
}

// ---- GEMM1: h = input @ hamilton (hi/lo split => ~fp32 accuracy)
// writes h^T bf16 (XOR-swizzled for attn LDS tiles) + s1s/s2s (scaled by log2e)
__global__ __launch_bounds__(256) void k_gemm1(
    const float* __restrict__ inp, const unsigned short* __restrict__ hamHi,
    const unsigned short* __restrict__ hamLo, const float* __restrict__ avec,
    unsigned short* __restrict__ hT, float* __restrict__ s1s, float* __restrict__ s2s){
  int i0 = blockIdx.x * 32;
  int w = threadIdx.x >> 6, lane = threadIdx.x & 63;
  int mi = lane & 15, g = lane >> 4;
  int cbase = w * 64;
  f32x4 acc[2][4];
#pragma unroll
  for (int mf=0; mf<2; ++mf)
#pragma unroll
    for (int nf=0; nf<4; ++nf) acc[mf][nf] = (f32x4){0.f,0.f,0.f,0.f};

  for (int k0 = 0; k0 < 1024; k0 += 32){
    short8 ah[2], al[2];
#pragma unroll
    for (int mf=0; mf<2; ++mf){
      const float* ap = inp + (size_t)(i0 + 16*mf + mi) * 1024 + k0 + 8*g;
      f32x4 x0 = *(const f32x4*)ap;
      f32x4 x1 = *(const f32x4*)(ap + 4);
#pragma unroll
      for (int e=0; e<8; ++e){
        float x = (e < 4) ? x0[e] : x1[e-4];
        unsigned short h = f2bf(x);
        ah[mf][e] = (short)h;
        al[mf][e] = (short)f2bf(x - bf2f(h));
      }
    }
    short8 bh[4], bl[4];
#pragma unroll
    for (int nf=0; nf<4; ++nf){
      size_t off = (size_t)(cbase + 16*nf + mi) * 1024 + k0 + 8*g;
      bh[nf] = *(const short8*)(hamHi + off);
      bl[nf] = *(const short8*)(hamLo + off);
    }
#pragma unroll
    for (int mf=0; mf<2; ++mf)
#pragma unroll
      for (int nf=0; nf<4; ++nf){
        acc[mf][nf] = __builtin_amdgcn_mfma_f32_16x16x32_bf16(ah[mf], bh[nf], acc[mf][nf], 0,0,0);
        acc[mf][nf] = __builtin_amdgcn_mfma_f32_16x16x32_bf16(ah[mf], bl[nf], acc[mf][nf], 0,0,0);
        acc[mf][nf] = __builtin_amdgcn_mfma_f32_16x16x32_bf16(al[mf], bh[nf], acc[mf][nf], 0,0,0);
      }
  }
  // epilogue: store h^T (bf16, swizzled) + s1/s2 reduction from fp32 acc
  float p1[2][4] = {{0,0,0,0},{0,0,0,0}}, p2[2][4] = {{0,0,0,0},{0,0,0,0}};
#pragma unroll
  for (int nf=0; nf<4; ++nf){
    int c = cbase + 16*nf + mi;
    float a1c = avec[c], a2c = avec[256 + c];
    int Sc = (c & 7) << 3;
#pragma unroll
    for (int mf=0; mf<2; ++mf){
      int ibase = i0 + 16*mf + 4*g;
      uint2v u;
      u[0] = (uint32_t)f2bf(acc[mf][nf][0]) | ((uint32_t)f2bf(acc[mf][nf][1]) << 16);
      u[1] = (uint32_t)f2bf(acc[mf][nf][2]) | ((uint32_t)f2bf(acc[mf][nf][3]) << 16);
      *(uint2v*)(hT + (size_t)c * 8192 + (size_t)(ibase ^ Sc)) = u;
#pragma unroll
      for (int rg=0; rg<4; ++rg){
        p1[mf][rg] += acc[mf][nf][rg] * a1c;
        p2[mf][rg] += acc[mf][nf][rg] * a2c;
      }
    }
  }
#pragma unroll
  for (int off=1; off<16; off<<=1){
#pragma unroll
    for (int mf=0; mf<2; ++mf)
#pragma unroll
      for (int rg=0; rg<4; ++rg){
        p1[mf][rg] += __shfl_xor(p1[mf][rg], off);
        p2[mf][rg] += __shfl_xor(p2[mf][rg], off);
      }
  }
  __shared__ float red1[4][32], red2[4][32];
  if (mi == 0){
#pragma unroll
    for (int mf=0; mf<2; ++mf)
#pragma unroll
      for (int rg=0; rg<4; ++rg){
        red1[w][16*mf + 4*g + rg] = p1[mf][rg];
        red2[w][16*mf + 4*g + rg] = p2[mf][rg];
      }
  }
  __syncthreads();
  if (threadIdx.x < 32){
    int r = threadIdx.x;
    float v1 = red1[0][r] + red1[1][r] + red1[2][r] + red1[3][r];
    float v2 = red2[0][r] + red2[1][r] + red2[2][r] + red2[3][r];
    s1s[i0 + r] = v1 * LOG2E;
    s2s[i0 + r] = v2 * LOG2E;
  }
}

// ---- global max of s2 (scaled) + zero stats accumulators ----
__global__ void k_max(const float* __restrict__ s2s, float* __restrict__ S2,
                      float* __restrict__ gsum, float* __restrict__ gsumsq){
  __shared__ float sm[256];
  int t = threadIdx.x;
  float m = -1e30f;
  for (int k = t; k < 8192; k += 256) m = fmaxf(m, s2s[k]);
  sm[t] = m; __syncthreads();
  for (int s = 128; s > 0; s >>= 1){ if (t < s) sm[t] = fmaxf(sm[t], sm[t+s]); __syncthreads(); }
  if (t == 0) S2[0] = sm[0];
  gsum[t] = 0.f; gsumsq[t] = 0.f;
}

// ---- fused masked-softmax @ h : streams adj ONCE, MFMA P@h ----
__global__ __launch_bounds__(256,2) void k_attn(
    const int* __restrict__ adj, const unsigned short* __restrict__ hT,
    const float* __restrict__ s1s, const float* __restrict__ s2s,
    const float* __restrict__ S2v, float* __restrict__ accg, float* __restrict__ Zg){
  __shared__ unsigned short hbuf[2][256*64];   // 64 KB double-buffered h^T tiles
  int rb = blockIdx.x, js = blockIdx.y;
  int w = threadIdx.x >> 6, lane = threadIdx.x & 63;
  int mi = lane & 15, g = lane >> 4;
  int i0w = rb * 128 + w * 32;
  int jw0 = js * 1024;
  float S2MAX = S2v[0];
  float s1v[2], m2[2];
#pragma unroll
  for (int mf=0; mf<2; ++mf){
    s1v[mf] = s1s[i0w + 16*mf + mi];
    float t = s1v[mf] + S2MAX;
    m2[mf] = t >= 0.f ? t : ALPHA * t;   // scaled lrelu of the global bound
  }
  f32x4 acc[2][16];
#pragma unroll
  for (int mf=0; mf<2; ++mf)
#pragma unroll
    for (int nf=0; nf<16; ++nf) acc[mf][nf] = (f32x4){0.f,0.f,0.f,0.f};
  float zac[2] = {0.f, 0.f};
  int tq = threadIdx.x & 7;
  int tn = threadIdx.x >> 3;
  // prologue: stage tile 0
#pragma unroll
  for (int r=0; r<8; ++r){
    int n = tn + 32*r;
    f32x4 v = *(const f32x4*)(hT + (size_t)n*8192 + jw0 + tq*8);
    *(f32x4*)&hbuf[0][n*64 + tq*8] = v;
  }
  __syncthreads();
  for (int tile = 0; tile < 16; ++tile){
    int buf = tile & 1;
    f32x4 vst[8];
    if (tile < 15){
#pragma unroll
      for (int r=0; r<8; ++r){
        int n = tn + 32*r;
        vst[r] = *(const f32x4*)(hT + (size_t)n*8192 + jw0 + (tile+1)*64 + tq*8);
      }
    }
#pragma unroll
    for (int ks=0; ks<2; ++ks){
      int jb = jw0 + tile*64 + ks*32;
      const float* s2p = s2s + jb + 8*g;
      f32x4 s20 = *(const f32x4*)s2p;
      f32x4 s21 = *(const f32x4*)(s2p + 4);
      short8 pa[2];
#pragma unroll
      for (int mf=0; mf<2; ++mf){
        const int* ap = adj + (size_t)(i0w + 16*mf + mi)*8192 + jb + 8*g;
        int4v a0 = *(const int4v*)ap;
        int4v a1 = *(const int4v*)(ap + 4);
#pragma unroll
        for (int e=0; e<8; ++e){
          float s2e = (e < 4) ? s20[e] : s21[e-4];
          int   ae  = (e < 4) ? a0[e]  : a1[e-4];
          float t = s1v[mf] + s2e;
          t = t >= 0.f ? t : ALPHA * t;
          float pe = (ae > 0) ? EXP2(t - m2[mf]) : 0.f;
          zac[mf] += pe;
          pa[mf][e] = (short)f2bf(pe);
        }
      }
      int goff = ((4*ks + g) ^ (mi & 7)) << 3;   // bank-conflict XOR swizzle
#pragma unroll
      for (int nf=0; nf<16; ++nf){
        short8 b = *(const short8*)&hbuf[buf][(16*nf + mi)*64 + goff];
        acc[0][nf] = __builtin_amdgcn_mfma_f32_16x16x32_bf16(pa[0], b, acc[0][nf], 0,0,0);
        acc[1][nf] = __builtin_amdgcn_mfma_f32_16x16x32_bf16(pa[1], b, acc[1][nf], 0,0,0);
      }
    }
    if (tile < 15){
#pragma unroll
      for (int r=0; r<8; ++r){
        int n = tn + 32*r;
        *(f32x4*)&hbuf[buf^1][n*64 + tq*8] = vst[r];
      }
    }
    __syncthreads();
  }
  // Z partial (sum over the 4 k-groups), add into global
#pragma unroll
  for (int mf=0; mf<2; ++mf){
    float z = zac[mf];
    z += __shfl_xor(z, 16);
    z += __shfl_xor(z, 32);
    if (lane < 16) atomicAdd(&Zg[i0w + 16*mf + lane], z);
  }
  // unnormalized h' partial
#pragma unroll
  for (int mf=0; mf<2; ++mf)
#pragma unroll
    for (int nf=0; nf<16; ++nf){
      int c  = 16*nf + mi;
      int ib = i0w + 16*mf + 4*g;
#pragma unroll
      for (int rg=0; rg<4; ++rg)
        atomicAdd(&accg[(size_t)(ib + rg)*256 + c], acc[mf][nf][rg]);
    }
}

// ---- normalize rows by Z, write h', accumulate column stats ----
__global__ void k_stats(const float* __restrict__ accg, const float* __restrict__ Zg,
                        float* __restrict__ hp, float* __restrict__ gsum,
                        float* __restrict__ gsumsq){
  int c = threadIdx.x;
  int r0 = blockIdx.x * 32;
  float s = 0.f, sq = 0.f;
  for (int r=0; r<32; ++r){
    int i = r0 + r;
    float z = Zg[i];
    float inv = (z > 0.f) ? 1.f / z : 0.f;
    float v = accg[(size_t)i*256 + c] * inv;
    hp[(size_t)i*256 + c] = v;
    s += v; sq += v*v;
  }
  atomicAdd(&gsum[c], s);
  atomicAdd(&gsumsq[c], sq);
}

// ---- batchnorm + elu, in-place on d_out ----
__global__ void k_bnelu(float* __restrict__ out, const float* __restrict__ gsum,
                        const float* __restrict__ gsumsq, const float* __restrict__ gamma,
                        const float* __restrict__ beta){
  int id = blockIdx.x * 256 + threadIdx.x;
  int c = id & 255;
  float mean = gsum[c] * (1.f/8192.f);
  float var  = gsumsq[c] * (1.f/8192.f) - mean*mean;
  float x = (out[id] - mean) * rsqrtf(var + 1e-5f) * gamma[c] + beta[c];
  out[id] = x > 0.f ? x : (EXP2(x * LOG2E) - 1.f);
}

extern "C" void kernel_launch(void* const* d_in, const int* in_sizes, int n_in,
                              void* d_out, int out_size, void* d_ws, size_t ws_size,
                              hipStream_t stream){
  const float* inp   = (const float*)d_in[0];
  const int*   adj   = (const int*)d_in[1];
  const float* W     = (const float*)d_in[2];
  const float* avec  = (const float*)d_in[3];
  const float* gamma = (const float*)d_in[4];
  const float* beta  = (const float*)d_in[5];
  float* out = (float*)d_out;

  char* ws = (char*)d_ws;
  float* accg = (float*)ws;                              // 2097152 f
  float* Zg   = accg + 2097152;                          // 8192 f
  unsigned short* hamHi = (unsigned short*)(Zg + 8192);  // 262144 bf16
  unsigned short* hamLo = hamHi + 262144;
  unsigned short* hT    = hamLo + 262144;                // 2097152 bf16
  float* s1s = (float*)(hT + 2097152);
  float* s2s = s1s + 8192;
  float* S2  = s2s + 8192;
  float* gsum   = S2 + 64;
  float* gsumsq = gsum + 256;

  k_zero<<<2056, 256, 0, stream>>>((f32x4*)ws);          // acc + Z
  k_ham<<<1024, 256, 0, stream>>>(W, hamHi, hamLo);
  k_gemm1<<<256, 256, 0, stream>>>(inp, hamHi, hamLo, avec, hT, s1s, s2s);
  k_max<<<1, 256, 0, stream>>>(s2s, S2, gsum, gsumsq);
  dim3 g3(64, 8);
  k_attn<<<g3, 256, 0, stream>>>(adj, hT, s1s, s2s, S2, accg, Zg);
  k_stats<<<256, 256, 0, stream>>>(accg, Zg, out, gsum, gsumsq);
  k_bnelu<<<8192, 256, 0, stream>>>(out, gsum, gsumsq, gamma, beta);
}

// Round 2
// 219.485 us; speedup vs baseline: 1.0471x; 1.0471x over previous
//
#include <hip/hip_runtime.h>
#include <stdint.h>

#define ALPHA 0.2f
#define LOG2E 1.4426950408889634f

typedef __attribute__((ext_vector_type(8))) short short8;
typedef __attribute__((ext_vector_type(4))) float f32x4;
typedef __attribute__((ext_vector_type(4))) int int4v;
typedef __attribute__((ext_vector_type(2))) unsigned int uint2v;

#if __has_builtin(__builtin_amdgcn_exp2f)
#define EXP2(x) __builtin_amdgcn_exp2f(x)
#else
#define EXP2(x) exp2f(x)
#endif

__device__ __forceinline__ unsigned short f2bf(float x){
  union { float f; uint32_t u; } v; v.f = x;
  uint32_t u = v.u;
  u += 0x7FFFu + ((u >> 16) & 1u);
  return (unsigned short)(u >> 16);
}
__device__ __forceinline__ float bf2f(unsigned short s){
  union { uint32_t u; float f; } v; v.u = ((uint32_t)s) << 16; return v.f;
}

// ---- zero acc + Z (8MB + 32KB) ----
__global__ void k_zero(f32x4* p){
  p[blockIdx.x * 256 + threadIdx.x] = (f32x4){0.f, 0.f, 0.f, 0.f};
}

// ---- hamilton^T as bf16 hi/lo planes: hamT[c][k], c<256, k<1024 ----
__global__ void k_ham(const float* __restrict__ W, unsigned short* __restrict__ hi,
                      unsigned short* __restrict__ lo){
  int id = blockIdx.x * 256 + threadIdx.x;   // id = c*1024 + k
  int c = id >> 10, k = id & 1023;
  int b = k >> 8, r = k & 255;
  int cb = c >> 6, col = c & 63;
  const int   comp[4][4] = {{0,1,2,3},{1,0,3,2},{2,3,0,1},{3,2,1,0}};
  const float sgn [4][4] = {{1.f,-1.f,-1.f,-1.f},{1.f,1.f,-1.f,1.f},
                            {1.f,1.f,1.f,-1.f},{1.f,-1.f,1.f,1.f}};
  float v = sgn[b][cb] * W[r * 256 + comp[b][cb] * 64 + col];
  unsigned short h = f2bf(v);
  hi[id] = h;
  lo[id] = f2bf(v - bf2f(h));
}

// ---- pack adj (int 0/1) into bitmask: bm[row*128 + j/64] bit (j%64) ----
// lane-transposed loads so each ballot covers 64 CONSECUTIVE ints.
__global__ void k_pack(const int* __restrict__ adj, unsigned long long* __restrict__ bm){
  const int lane = threadIdx.x & 63;
  const size_t t = (size_t)blockIdx.x * 256 + threadIdx.x;
  const size_t wbase = (t & ~(size_t)63) * 16;   // 1024 ints per wave
  int a[16];
#pragma unroll
  for (int q = 0; q < 16; ++q) a[q] = adj[wbase + (size_t)q * 64 + lane];
  unsigned long long b[16];
#pragma unroll
  for (int q = 0; q < 16; ++q) b[q] = __ballot(a[q] > 0);
  if (lane < 16){
    unsigned long long v = b[0];
#pragma unroll
    for (int q = 1; q < 16; ++q) v = (lane == q) ? b[q] : v;
    bm[wbase / 64 + lane] = v;
  }
}

// ---- GEMM1: h = input @ hamilton (hi/lo split => ~fp32 accuracy)
// writes h^T bf16 (XOR-swizzled for attn LDS tiles) + s1s/s2s (scaled by log2e)
__global__ __launch_bounds__(256) void k_gemm1(
    const float* __restrict__ inp, const unsigned short* __restrict__ hamHi,
    const unsigned short* __restrict__ hamLo, const float* __restrict__ avec,
    unsigned short* __restrict__ hT, float* __restrict__ s1s, float* __restrict__ s2s){
  int i0 = blockIdx.x * 32;
  int w = threadIdx.x >> 6, lane = threadIdx.x & 63;
  int mi = lane & 15, g = lane >> 4;
  int cbase = w * 64;
  f32x4 acc[2][4];
#pragma unroll
  for (int mf=0; mf<2; ++mf)
#pragma unroll
    for (int nf=0; nf<4; ++nf) acc[mf][nf] = (f32x4){0.f,0.f,0.f,0.f};

  for (int k0 = 0; k0 < 1024; k0 += 32){
    short8 ah[2], al[2];
#pragma unroll
    for (int mf=0; mf<2; ++mf){
      const float* ap = inp + (size_t)(i0 + 16*mf + mi) * 1024 + k0 + 8*g;
      f32x4 x0 = *(const f32x4*)ap;
      f32x4 x1 = *(const f32x4*)(ap + 4);
#pragma unroll
      for (int e=0; e<8; ++e){
        float x = (e < 4) ? x0[e] : x1[e-4];
        unsigned short h = f2bf(x);
        ah[mf][e] = (short)h;
        al[mf][e] = (short)f2bf(x - bf2f(h));
      }
    }
    short8 bh[4], bl[4];
#pragma unroll
    for (int nf=0; nf<4; ++nf){
      size_t off = (size_t)(cbase + 16*nf + mi) * 1024 + k0 + 8*g;
      bh[nf] = *(const short8*)(hamHi + off);
      bl[nf] = *(const short8*)(hamLo + off);
    }
#pragma unroll
    for (int mf=0; mf<2; ++mf)
#pragma unroll
      for (int nf=0; nf<4; ++nf){
        acc[mf][nf] = __builtin_amdgcn_mfma_f32_16x16x32_bf16(ah[mf], bh[nf], acc[mf][nf], 0,0,0);
        acc[mf][nf] = __builtin_amdgcn_mfma_f32_16x16x32_bf16(ah[mf], bl[nf], acc[mf][nf], 0,0,0);
        acc[mf][nf] = __builtin_amdgcn_mfma_f32_16x16x32_bf16(al[mf], bh[nf], acc[mf][nf], 0,0,0);
      }
  }
  float p1[2][4] = {{0,0,0,0},{0,0,0,0}}, p2[2][4] = {{0,0,0,0},{0,0,0,0}};
#pragma unroll
  for (int nf=0; nf<4; ++nf){
    int c = cbase + 16*nf + mi;
    float a1c = avec[c], a2c = avec[256 + c];
    int Sc = (c & 7) << 3;
#pragma unroll
    for (int mf=0; mf<2; ++mf){
      int ibase = i0 + 16*mf + 4*g;
      uint2v u;
      u[0] = (uint32_t)f2bf(acc[mf][nf][0]) | ((uint32_t)f2bf(acc[mf][nf][1]) << 16);
      u[1] = (uint32_t)f2bf(acc[mf][nf][2]) | ((uint32_t)f2bf(acc[mf][nf][3]) << 16);
      *(uint2v*)(hT + (size_t)c * 8192 + (size_t)(ibase ^ Sc)) = u;
#pragma unroll
      for (int rg=0; rg<4; ++rg){
        p1[mf][rg] += acc[mf][nf][rg] * a1c;
        p2[mf][rg] += acc[mf][nf][rg] * a2c;
      }
    }
  }
#pragma unroll
  for (int off=1; off<16; off<<=1){
#pragma unroll
    for (int mf=0; mf<2; ++mf)
#pragma unroll
      for (int rg=0; rg<4; ++rg){
        p1[mf][rg] += __shfl_xor(p1[mf][rg], off);
        p2[mf][rg] += __shfl_xor(p2[mf][rg], off);
      }
  }
  __shared__ float red1[4][32], red2[4][32];
  if (mi == 0){
#pragma unroll
    for (int mf=0; mf<2; ++mf)
#pragma unroll
      for (int rg=0; rg<4; ++rg){
        red1[w][16*mf + 4*g + rg] = p1[mf][rg];
        red2[w][16*mf + 4*g + rg] = p2[mf][rg];
      }
  }
  __syncthreads();
  if (threadIdx.x < 32){
    int r = threadIdx.x;
    float v1 = red1[0][r] + red1[1][r] + red1[2][r] + red1[3][r];
    float v2 = red2[0][r] + red2[1][r] + red2[2][r] + red2[3][r];
    s1s[i0 + r] = v1 * LOG2E;
    s2s[i0 + r] = v2 * LOG2E;
  }
}

// ---- global max of s2 (scaled) + zero stats accumulators ----
__global__ void k_max(const float* __restrict__ s2s, float* __restrict__ S2,
                      float* __restrict__ gsum, float* __restrict__ gsumsq){
  __shared__ float sm[256];
  int t = threadIdx.x;
  float m = -1e30f;
  for (int k = t; k < 8192; k += 256) m = fmaxf(m, s2s[k]);
  sm[t] = m; __syncthreads();
  for (int s = 128; s > 0; s >>= 1){ if (t < s) sm[t] = fmaxf(sm[t], sm[t+s]); __syncthreads(); }
  if (t == 0) S2[0] = sm[0];
  gsum[t] = 0.f; gsumsq[t] = 0.f;
}

// stage hT tile t into hbuf[b]: linear tid*16B dest == wave-uniform base + lane*16
#define STAGE(t, b) do { \
    _Pragma("unroll") \
    for (int r_ = 0; r_ < 8; ++r_){ \
      const unsigned short* gp_ = hT + (size_t)((tid>>3) + 32*r_)*8192 + jw0 + (t)*64 + (tid&7)*8; \
      __builtin_amdgcn_global_load_lds((const __attribute__((address_space(1))) void*)(const void*)gp_, \
          (__attribute__((address_space(3))) void*)(void*)&hbuf[(b)][tid*8 + r_*2048], 16, 0, 0); \
    } } while(0)

// ---- fused masked-softmax @ h : bitmask-masked, tile-ahead prefetch ----
__global__ __launch_bounds__(256,2) void k_attn(
    const unsigned long long* __restrict__ bm, const unsigned short* __restrict__ hT,
    const float* __restrict__ s1s, const float* __restrict__ s2s,
    const float* __restrict__ S2v, float* __restrict__ accg, float* __restrict__ Zg){
  __shared__ unsigned short hbuf[2][256*64];   // 64 KB double-buffered h^T tiles
  __shared__ float s2l[1024];                  // 4 KB s2 slice for this j-range
  const int tid = threadIdx.x;
  const int rb = blockIdx.x, js = blockIdx.y;
  const int w = tid >> 6, lane = tid & 63;
  const int mi = lane & 15, g = lane >> 4;
  const int i0w = rb * 128 + w * 32;
  const int jw0 = js * 1024;

  { f32x4 v = *(const f32x4*)(s2s + jw0 + tid*4); *(f32x4*)&s2l[tid*4] = v; }

  float S2MAX = S2v[0];
  float s1v[2], m2[2];
#pragma unroll
  for (int mf=0; mf<2; ++mf){
    s1v[mf] = s1s[i0w + 16*mf + mi];
    float x = s1v[mf] + S2MAX;
    m2[mf] = fmaxf(x, ALPHA * x);   // scaled lrelu of the global bound
  }
  const unsigned long long* brow[2] = {
    bm + (size_t)(i0w + mi) * 128 + (jw0 >> 6),
    bm + (size_t)(i0w + 16 + mi) * 128 + (jw0 >> 6) };

  f32x4 acc[2][16];
#pragma unroll
  for (int mf=0; mf<2; ++mf)
#pragma unroll
    for (int nf=0; nf<16; ++nf) acc[mf][nf] = (f32x4){0.f,0.f,0.f,0.f};
  float zac[2] = {0.f, 0.f};

  unsigned long long bA0 = brow[0][0], bA1 = brow[1][0];
  unsigned long long bB0 = 0, bB1 = 0;
  STAGE(0, 0);
  __syncthreads();

  for (int tile = 0; tile < 16; ++tile){
    const int buf = tile & 1;
    if (tile < 15){
      STAGE(tile + 1, buf ^ 1);
      bB0 = brow[0][tile + 1];
      bB1 = brow[1][tile + 1];
    }
#pragma unroll
    for (int ks=0; ks<2; ++ks){
      f32x4 sa = *(const f32x4*)&s2l[tile*64 + ks*32 + 8*g];
      f32x4 sb = *(const f32x4*)&s2l[tile*64 + ks*32 + 8*g + 4];
      short8 pa[2];
#pragma unroll
      for (int mf=0; mf<2; ++mf){
        unsigned int w32 = (unsigned int)((mf ? bA1 : bA0) >> (32*ks));
#pragma unroll
        for (int e=0; e<8; ++e){
          float s2e = (e < 4) ? sa[e] : sb[e-4];
          float x = s1v[mf] + s2e;
          float t = fmaxf(x, ALPHA * x);
          float pe = EXP2(t - m2[mf]);
          pe = ((w32 >> (8*g + e)) & 1u) ? pe : 0.f;
          zac[mf] += pe;
          pa[mf][e] = (short)f2bf(pe);
        }
      }
      const int goff = ((4*ks + g) ^ (mi & 7)) << 3;   // matches gemm1 pre-swizzle
#pragma unroll
      for (int nf=0; nf<16; ++nf){
        short8 b = *(const short8*)&hbuf[buf][(16*nf + mi)*64 + goff];
        acc[0][nf] = __builtin_amdgcn_mfma_f32_16x16x32_bf16(pa[0], b, acc[0][nf], 0,0,0);
        acc[1][nf] = __builtin_amdgcn_mfma_f32_16x16x32_bf16(pa[1], b, acc[1][nf], 0,0,0);
      }
    }
    bA0 = bB0; bA1 = bB1;
    __syncthreads();
  }
  // Z partial (sum over the 4 k-groups), add into global
#pragma unroll
  for (int mf=0; mf<2; ++mf){
    float z = zac[mf];
    z += __shfl_xor(z, 16);
    z += __shfl_xor(z, 32);
    if (lane < 16) atomicAdd(&Zg[i0w + 16*mf + lane], z);
  }
  // unnormalized h' partial
#pragma unroll
  for (int mf=0; mf<2; ++mf)
#pragma unroll
    for (int nf=0; nf<16; ++nf){
      int c  = 16*nf + mi;
      int ib = i0w + 16*mf + 4*g;
#pragma unroll
      for (int rg=0; rg<4; ++rg)
        atomicAdd(&accg[(size_t)(ib + rg)*256 + c], acc[mf][nf][rg]);
    }
}

// ---- normalize rows by Z, write h', accumulate column stats ----
__global__ void k_stats(const float* __restrict__ accg, const float* __restrict__ Zg,
                        float* __restrict__ hp, float* __restrict__ gsum,
                        float* __restrict__ gsumsq){
  int c = threadIdx.x;
  int r0 = blockIdx.x * 32;
  float s = 0.f, sq = 0.f;
  for (int r=0; r<32; ++r){
    int i = r0 + r;
    float z = Zg[i];
    float inv = (z > 0.f) ? 1.f / z : 0.f;
    float v = accg[(size_t)i*256 + c] * inv;
    hp[(size_t)i*256 + c] = v;
    s += v; sq += v*v;
  }
  atomicAdd(&gsum[c], s);
  atomicAdd(&gsumsq[c], sq);
}

// ---- batchnorm + elu, in-place on d_out ----
__global__ void k_bnelu(float* __restrict__ out, const float* __restrict__ gsum,
                        const float* __restrict__ gsumsq, const float* __restrict__ gamma,
                        const float* __restrict__ beta){
  int id = blockIdx.x * 256 + threadIdx.x;
  int c = id & 255;
  float mean = gsum[c] * (1.f/8192.f);
  float var  = gsumsq[c] * (1.f/8192.f) - mean*mean;
  float x = (out[id] - mean) * rsqrtf(var + 1e-5f) * gamma[c] + beta[c];
  out[id] = x > 0.f ? x : (EXP2(x * LOG2E) - 1.f);
}

extern "C" void kernel_launch(void* const* d_in, const int* in_sizes, int n_in,
                              void* d_out, int out_size, void* d_ws, size_t ws_size,
                              hipStream_t stream){
  const float* inp   = (const float*)d_in[0];
  const int*   adj   = (const int*)d_in[1];
  const float* W     = (const float*)d_in[2];
  const float* avec  = (const float*)d_in[3];
  const float* gamma = (const float*)d_in[4];
  const float* beta  = (const float*)d_in[5];
  float* out = (float*)d_out;

  char* ws = (char*)d_ws;
  float* accg = (float*)ws;                              // 2097152 f
  float* Zg   = accg + 2097152;                          // 8192 f
  unsigned short* hamHi = (unsigned short*)(Zg + 8192);  // 262144 bf16
  unsigned short* hamLo = hamHi + 262144;
  unsigned short* hT    = hamLo + 262144;                // 2097152 bf16
  float* s1s = (float*)(hT + 2097152);
  float* s2s = s1s + 8192;
  float* S2  = s2s + 8192;
  float* gsum   = S2 + 64;
  float* gsumsq = gsum + 256;
  unsigned long long* bm = (unsigned long long*)(gsumsq + 256);  // 1M u64 = 8MB

  k_zero<<<2056, 256, 0, stream>>>((f32x4*)ws);          // acc + Z
  k_ham<<<1024, 256, 0, stream>>>(W, hamHi, hamLo);
  k_pack<<<16384, 256, 0, stream>>>(adj, bm);
  k_gemm1<<<256, 256, 0, stream>>>(inp, hamHi, hamLo, avec, hT, s1s, s2s);
  k_max<<<1, 256, 0, stream>>>(s2s, S2, gsum, gsumsq);
  dim3 g3(64, 8);
  k_attn<<<g3, 256, 0, stream>>>(bm, hT, s1s, s2s, S2, accg, Zg);
  k_stats<<<256, 256, 0, stream>>>(accg, Zg, out, gsum, gsumsq);
  k_bnelu<<<8192, 256, 0, stream>>>(out, gsum, gsumsq, gamma, beta);
}

// Round 3
// 182.957 us; speedup vs baseline: 1.2561x; 1.1997x over previous
//
#include <hip/hip_runtime.h>
#include <stdint.h>

#define ALPHA 0.2f
#define LOG2E 1.4426950408889634f

typedef __attribute__((ext_vector_type(8))) short short8;
typedef __attribute__((ext_vector_type(4))) float f32x4;
typedef __attribute__((ext_vector_type(4))) int int4v;
typedef __attribute__((ext_vector_type(2))) unsigned int uint2v;

#if __has_builtin(__builtin_amdgcn_exp2f)
#define EXP2(x) __builtin_amdgcn_exp2f(x)
#else
#define EXP2(x) exp2f(x)
#endif

__device__ __forceinline__ unsigned short f2bf(float x){
  union { float f; uint32_t u; } v; v.f = x;
  uint32_t u = v.u;
  u += 0x7FFFu + ((u >> 16) & 1u);
  return (unsigned short)(u >> 16);
}
__device__ __forceinline__ float bf2f(unsigned short s){
  union { uint32_t u; float f; } v; v.u = ((uint32_t)s) << 16; return v.f;
}
// order-preserving f32 <-> u32 (for atomicMax); 0 is below every real encoding
__device__ __forceinline__ unsigned encf(float x){
  unsigned u = __float_as_uint(x);
  return (u & 0x80000000u) ? ~u : (u | 0x80000000u);
}
__device__ __forceinline__ float decf(unsigned u){
  return (u & 0x80000000u) ? __uint_as_float(u & 0x7FFFFFFFu) : __uint_as_float(~u);
}

// ---- hamilton^T as bf16 hi/lo planes: hamT[c][k], c<256, k<1024 ----
__global__ void k_ham(const float* __restrict__ W, unsigned short* __restrict__ hi,
                      unsigned short* __restrict__ lo){
  int id = blockIdx.x * 256 + threadIdx.x;   // id = c*1024 + k
  int c = id >> 10, k = id & 1023;
  int b = k >> 8, r = k & 255;
  int cb = c >> 6, col = c & 63;
  const int   comp[4][4] = {{0,1,2,3},{1,0,3,2},{2,3,0,1},{3,2,1,0}};
  const float sgn [4][4] = {{1.f,-1.f,-1.f,-1.f},{1.f,1.f,-1.f,1.f},
                            {1.f,1.f,1.f,-1.f},{1.f,-1.f,1.f,1.f}};
  float v = sgn[b][cb] * W[r * 256 + comp[b][cb] * 64 + col];
  unsigned short h = f2bf(v);
  hi[id] = h;
  lo[id] = f2bf(v - bf2f(h));
}

// ---- pack adj (int 0/1) into bitmask, dwordx4 loads, permuted bit layout ----
// word[row*128 + (j>>8)*4 + (j&3)], bit ((j>>2)&63)  <- j = column index
__global__ void k_pack(const int* __restrict__ adj, unsigned long long* __restrict__ bm,
                       unsigned* __restrict__ S2enc, float* __restrict__ gsum,
                       float* __restrict__ gsumsq){
  if (blockIdx.x == 0){
    if (threadIdx.x == 0) S2enc[0] = 0u;
    gsum[threadIdx.x] = 0.f; gsumsq[threadIdx.x] = 0.f;
  }
  const int lane = threadIdx.x & 63;
  const size_t wid = ((size_t)blockIdx.x * 256 + threadIdx.x) >> 6;
  const size_t W0 = wid * 1024;                 // 1024 consecutive elems per wave
  unsigned long long b[16];
#pragma unroll
  for (int q = 0; q < 4; ++q){
    int4v a = *(const int4v*)(adj + W0 + 256*q + 4*lane);
#pragma unroll
    for (int k = 0; k < 4; ++k) b[4*q + k] = __ballot(a[k] > 0);
  }
  if (lane < 16){
    unsigned long long v = b[0];
#pragma unroll
    for (int m = 1; m < 16; ++m) v = (lane == m) ? b[m] : v;
    bm[W0/64 + lane] = v;
  }
}

// ---- GEMM1: h = input @ hamilton (hi/lo split => ~fp32 accuracy)
// writes h^T bf16 (XOR-swizzled) + s1s/s2s (scaled by log2e) + global max(s2s)
__global__ __launch_bounds__(256) void k_gemm1(
    const float* __restrict__ inp, const unsigned short* __restrict__ hamHi,
    const unsigned short* __restrict__ hamLo, const float* __restrict__ avec,
    unsigned short* __restrict__ hT, float* __restrict__ s1s, float* __restrict__ s2s,
    unsigned* __restrict__ S2enc){
  int i0 = blockIdx.x * 32;
  int w = threadIdx.x >> 6, lane = threadIdx.x & 63;
  int mi = lane & 15, g = lane >> 4;
  int cbase = w * 64;
  f32x4 acc[2][4];
#pragma unroll
  for (int mf=0; mf<2; ++mf)
#pragma unroll
    for (int nf=0; nf<4; ++nf) acc[mf][nf] = (f32x4){0.f,0.f,0.f,0.f};

  for (int k0 = 0; k0 < 1024; k0 += 32){
    short8 ah[2], al[2];
#pragma unroll
    for (int mf=0; mf<2; ++mf){
      const float* ap = inp + (size_t)(i0 + 16*mf + mi) * 1024 + k0 + 8*g;
      f32x4 x0 = *(const f32x4*)ap;
      f32x4 x1 = *(const f32x4*)(ap + 4);
#pragma unroll
      for (int e=0; e<8; ++e){
        float x = (e < 4) ? x0[e] : x1[e-4];
        unsigned short h = f2bf(x);
        ah[mf][e] = (short)h;
        al[mf][e] = (short)f2bf(x - bf2f(h));
      }
    }
    short8 bh[4], bl[4];
#pragma unroll
    for (int nf=0; nf<4; ++nf){
      size_t off = (size_t)(cbase + 16*nf + mi) * 1024 + k0 + 8*g;
      bh[nf] = *(const short8*)(hamHi + off);
      bl[nf] = *(const short8*)(hamLo + off);
    }
#pragma unroll
    for (int mf=0; mf<2; ++mf)
#pragma unroll
      for (int nf=0; nf<4; ++nf){
        acc[mf][nf] = __builtin_amdgcn_mfma_f32_16x16x32_bf16(ah[mf], bh[nf], acc[mf][nf], 0,0,0);
        acc[mf][nf] = __builtin_amdgcn_mfma_f32_16x16x32_bf16(ah[mf], bl[nf], acc[mf][nf], 0,0,0);
        acc[mf][nf] = __builtin_amdgcn_mfma_f32_16x16x32_bf16(al[mf], bh[nf], acc[mf][nf], 0,0,0);
      }
  }
  float p1[2][4] = {{0,0,0,0},{0,0,0,0}}, p2[2][4] = {{0,0,0,0},{0,0,0,0}};
#pragma unroll
  for (int nf=0; nf<4; ++nf){
    int c = cbase + 16*nf + mi;
    float a1c = avec[c], a2c = avec[256 + c];
    int Sc = (c & 7) << 3;
#pragma unroll
    for (int mf=0; mf<2; ++mf){
      int ibase = i0 + 16*mf + 4*g;
      uint2v u;
      u[0] = (uint32_t)f2bf(acc[mf][nf][0]) | ((uint32_t)f2bf(acc[mf][nf][1]) << 16);
      u[1] = (uint32_t)f2bf(acc[mf][nf][2]) | ((uint32_t)f2bf(acc[mf][nf][3]) << 16);
      *(uint2v*)(hT + (size_t)c * 8192 + (size_t)(ibase ^ Sc)) = u;
#pragma unroll
      for (int rg=0; rg<4; ++rg){
        p1[mf][rg] += acc[mf][nf][rg] * a1c;
        p2[mf][rg] += acc[mf][nf][rg] * a2c;
      }
    }
  }
#pragma unroll
  for (int off=1; off<16; off<<=1){
#pragma unroll
    for (int mf=0; mf<2; ++mf)
#pragma unroll
      for (int rg=0; rg<4; ++rg){
        p1[mf][rg] += __shfl_xor(p1[mf][rg], off);
        p2[mf][rg] += __shfl_xor(p2[mf][rg], off);
      }
  }
  __shared__ float red1[4][32], red2[4][32];
  if (mi == 0){
#pragma unroll
    for (int mf=0; mf<2; ++mf)
#pragma unroll
      for (int rg=0; rg<4; ++rg){
        red1[w][16*mf + 4*g + rg] = p1[mf][rg];
        red2[w][16*mf + 4*g + rg] = p2[mf][rg];
      }
  }
  __syncthreads();
  if (threadIdx.x < 32){
    int r = threadIdx.x;
    float v1 = red1[0][r] + red1[1][r] + red1[2][r] + red1[3][r];
    float v2 = red2[0][r] + red2[1][r] + red2[2][r] + red2[3][r];
    s1s[i0 + r] = v1 * LOG2E;
    float v2s = v2 * LOG2E;
    s2s[i0 + r] = v2s;
    float m = v2s;
#pragma unroll
    for (int off=1; off<32; off<<=1) m = fmaxf(m, __shfl_xor(m, off));
    if (r == 0) atomicMax(S2enc, encf(m));
  }
}

// stage hT tile t (256c x 64j, 32KB) into hbuf[b]; linear LDS dest = lane*16
#define STAGE(t, b) do { \
    _Pragma("unroll") \
    for (int r_ = 0; r_ < 4; ++r_){ \
      int ch_ = tid + r_*512; \
      const unsigned short* gp_ = hT + (size_t)(ch_ >> 3)*8192 + jw0 + (t)*64 + (ch_&7)*8; \
      __builtin_amdgcn_global_load_lds((const __attribute__((address_space(1))) void*)(const void*)gp_, \
          (__attribute__((address_space(3))) void*)(void*)&hbuf[(b)][tid*8 + r_*4096], 16, 0, 0); \
    } } while(0)

// ---- fused masked-softmax @ h : private partials, no atomics ----
__global__ __launch_bounds__(512,2) void k_attn(
    const unsigned long long* __restrict__ bm, const unsigned short* __restrict__ hT,
    const float* __restrict__ s1s, const float* __restrict__ s2s,
    const unsigned* __restrict__ S2enc, float* __restrict__ accp, float* __restrict__ Zp){
  __shared__ unsigned short hbuf[2][256*64];   // 64 KB double-buffered h^T tiles
  __shared__ float s2l[2048];                  // 8 KB s2 slice
  const int tid = threadIdx.x;
  const int id = blockIdx.x;
  // XCD swizzle: each XCD owns one js slice (hT slice + bm slice stay L2-hot)
  const int js = (id & 7) >> 1;
  const int rb = ((id >> 3) << 1) | (id & 1);
  const int w = tid >> 6, lane = tid & 63;
  const int mi = lane & 15, g = lane >> 4;
  const int i0w = rb * 128 + w * 16;
  const int jw0 = js * 2048;

  { f32x4 v = *(const f32x4*)(s2s + jw0 + tid*4); *(f32x4*)&s2l[tid*4] = v; }

  float S2MAX = decf(S2enc[0]);
  float s1v = s1s[i0w + mi];
  float xm = s1v + S2MAX;
  float m2 = fmaxf(xm, ALPHA * xm);            // scaled lrelu of the global bound

  const unsigned long long* brow = bm + (size_t)(i0w + mi) * 128 + (jw0 >> 8) * 4;

  f32x4 acc[16];
#pragma unroll
  for (int nf=0; nf<16; ++nf) acc[nf] = (f32x4){0.f,0.f,0.f,0.f};
  float zac = 0.f;

  unsigned long long Wc[4], Wn[4];
#pragma unroll
  for (int k=0;k<4;++k) Wc[k] = brow[k];
  STAGE(0, 0);
  __syncthreads();

  for (int tile = 0; tile < 32; ++tile){
    const int buf = tile & 1;
    if ((tile & 3) == 0){
      if (tile){
#pragma unroll
        for (int k=0;k<4;++k) Wc[k] = Wn[k];
      }
      if (tile + 4 < 32){
        const unsigned long long* p = brow + (tile >> 2)*4 + 4;
#pragma unroll
        for (int k=0;k<4;++k) Wn[k] = p[k];
      }
    }
    if (tile < 31) STAGE(tile + 1, buf ^ 1);
    const int base16 = (tile & 3) << 4;
#pragma unroll
    for (int ks=0; ks<2; ++ks){
      f32x4 sa = *(const f32x4*)&s2l[tile*64 + ks*32 + 8*g];
      f32x4 sb = *(const f32x4*)&s2l[tile*64 + ks*32 + 8*g + 4];
      const int sh0 = base16 + ks*8 + 2*g;
      unsigned tt[4];
#pragma unroll
      for (int k=0;k<4;++k) tt[k] = (unsigned)(Wc[k] >> sh0);
      short8 pa;
#pragma unroll
      for (int e=0; e<8; ++e){
        float s2e = (e < 4) ? sa[e] : sb[e-4];
        float x = s1v + s2e;
        float t = fmaxf(x, ALPHA * x);
        float pe = EXP2(t - m2);
        pe = ((tt[e & 3] >> (e >> 2)) & 1u) ? pe : 0.f;
        zac += pe;
        pa[e] = (short)f2bf(pe);
      }
      const int goff = ((4*ks + g) ^ (mi & 7)) << 3;   // matches gemm1 pre-swizzle
#pragma unroll
      for (int nf=0; nf<16; ++nf){
        short8 b = *(const short8*)&hbuf[buf][(16*nf + mi)*64 + goff];
        acc[nf] = __builtin_amdgcn_mfma_f32_16x16x32_bf16(pa, b, acc[nf], 0,0,0);
      }
    }
    __syncthreads();
  }
  // Z partial: sum over g groups -> unique (js,row) slot, plain store
  {
    float z = zac;
    z += __shfl_xor(z, 16);
    z += __shfl_xor(z, 32);
    if (lane < 16) Zp[js*8192 + i0w + lane] = z;
  }
  // unnormalized h' partial: unique (js,row,c) slots, plain stores
#pragma unroll
  for (int nf=0; nf<16; ++nf){
    int c = 16*nf + mi;
#pragma unroll
    for (int rg=0; rg<4; ++rg)
      accp[(size_t)(js*8192 + i0w + 4*g + rg)*256 + c] = acc[nf][rg];
  }
}

// ---- reduce 4 partials, normalize by Z, write h', accumulate column stats ----
__global__ void k_stats(const float* __restrict__ accp, const float* __restrict__ Zp,
                        float* __restrict__ hp, float* __restrict__ gsum,
                        float* __restrict__ gsumsq){
  int c = threadIdx.x;
  int r0 = blockIdx.x * 32;
  float s = 0.f, sq = 0.f;
  for (int r=0; r<32; ++r){
    int i = r0 + r;
    float z = Zp[i] + Zp[8192 + i] + Zp[16384 + i] + Zp[24576 + i];
    float inv = (z > 0.f) ? 1.f / z : 0.f;
    size_t o = (size_t)i * 256 + c;
    float v = (accp[o] + accp[o + 8192*256] + accp[o + 2*8192*256] + accp[o + 3*8192*256]) * inv;
    hp[o] = v;
    s += v; sq += v*v;
  }
  atomicAdd(&gsum[c], s);
  atomicAdd(&gsumsq[c], sq);
}

// ---- batchnorm + elu, in-place on d_out ----
__global__ void k_bnelu(float* __restrict__ out, const float* __restrict__ gsum,
                        const float* __restrict__ gsumsq, const float* __restrict__ gamma,
                        const float* __restrict__ beta){
  int id = blockIdx.x * 256 + threadIdx.x;
  int c = id & 255;
  float mean = gsum[c] * (1.f/8192.f);
  float var  = gsumsq[c] * (1.f/8192.f) - mean*mean;
  float x = (out[id] - mean) * rsqrtf(var + 1e-5f) * gamma[c] + beta[c];
  out[id] = x > 0.f ? x : (EXP2(x * LOG2E) - 1.f);
}

extern "C" void kernel_launch(void* const* d_in, const int* in_sizes, int n_in,
                              void* d_out, int out_size, void* d_ws, size_t ws_size,
                              hipStream_t stream){
  const float* inp   = (const float*)d_in[0];
  const int*   adj   = (const int*)d_in[1];
  const float* W     = (const float*)d_in[2];
  const float* avec  = (const float*)d_in[3];
  const float* gamma = (const float*)d_in[4];
  const float* beta  = (const float*)d_in[5];
  float* out = (float*)d_out;

  char* ws = (char*)d_ws;
  float* accp = (float*)ws;                               // 4*8192*256 f = 32 MB
  float* Zp   = accp + 4*8192*256;                        // 32768 f
  unsigned short* hamHi = (unsigned short*)(Zp + 32768);  // 262144 bf16
  unsigned short* hamLo = hamHi + 262144;
  unsigned short* hT    = hamLo + 262144;                 // 2097152 bf16
  float* s1s = (float*)(hT + 2097152);
  float* s2s = s1s + 8192;
  unsigned* S2enc = (unsigned*)(s2s + 8192);
  float* gsum   = (float*)(S2enc + 64);
  float* gsumsq = gsum + 256;
  unsigned long long* bm = (unsigned long long*)(gsumsq + 256);  // 1M u64 = 8MB

  k_ham<<<1024, 256, 0, stream>>>(W, hamHi, hamLo);
  k_pack<<<16384, 256, 0, stream>>>(adj, bm, S2enc, gsum, gsumsq);
  k_gemm1<<<256, 256, 0, stream>>>(inp, hamHi, hamLo, avec, hT, s1s, s2s, S2enc);
  k_attn<<<256, 512, 0, stream>>>(bm, hT, s1s, s2s, S2enc, accp, Zp);
  k_stats<<<256, 256, 0, stream>>>(accp, Zp, out, gsum, gsumsq);
  k_bnelu<<<8192, 256, 0, stream>>>(out, gsum, gsumsq, gamma, beta);
}